// Round 17
// baseline (23.246 us; speedup 1.0000x reference)
//
#include <hip/hip_runtime.h>

#define HH 2048
#define WW 2048
#define OH 512
#define OW 512
#define TKC 32               // output cols per tile
#define TKR 16               // output rows per tile (8 waves x 2 rows)
#define NBLK 512             // 2 blocks/CU, all resident
#define TPB 3                // 512*3 = 1536 = 3ch * 16tcc * 32trr
#define WROWS 14             // s-rows per wave (2 out rows -> 8..13 window)
#define WSZF (WROWS * TKC * 4)   // 1792 floats = 7 KB per wave
#define LDSF (8 * WSZF)          // 57.3 KB per 512-thread block

#define SCHED0()   __builtin_amdgcn_sched_barrier(0)
#define WAITV(n)   asm volatile("s_waitcnt vmcnt(" #n ")" ::: "memory")
#define WAITLGKM() asm volatile("s_waitcnt lgkmcnt(0)" ::: "memory")

__device__ __forceinline__ float rfl(float v) {
    return __int_as_float(__builtin_amdgcn_readfirstlane(__float_as_int(v)));
}

// Zero-barrier design: each wave owns a private 14x32x4 s-region; row-filter
// results never cross waves, so write->read visibility needs only lgkmcnt(0)
// (wave-level). 16 independent wave pipelines per CU, no phase coupling.
__global__ __launch_bounds__(512, 4)
void wpt2_kernel(const float* __restrict__ x,
                 const float* __restrict__ dec_lo,
                 const float* __restrict__ dec_hi,
                 float* __restrict__ out) {
    __shared__ float sbuf[LDSF];

    const int tid  = threadIdx.x;         // 0..511
    const int w    = tid >> 6;            // wave 0..7 -> out rows 2w, 2w+1
    const int lane = tid & 63;
    const int tx   = lane & 31;           // output col within tile
    const int typ  = lane >> 5;           // 0/1: which of the wave's 2 rows
    float* const ws = &sbuf[w * WSZF];    // wave-private region

    // bijective XCD swizzle (512 % 8 == 0)
    const int bid = blockIdx.x;
    const int swz = (bid & 7) * (NBLK / 8) + (bid >> 3);
    const int tile0 = swz * TPB;          // tileId = (ch*16 + tcc)*32 + trr

    // ---- composed 10-tap filters (graycode band order), pinned to SGPRs ----
    float lo[4], hi[4];
#pragma unroll
    for (int j = 0; j < 4; ++j) { lo[j] = dec_lo[j]; hi[j] = dec_hi[j]; }
    float F[4][10];
#pragma unroll
    for (int g = 0; g < 4; ++g) {
        const float* f1 = (g >= 2) ? hi : lo;             // level-1: 0,0,1,1
        const float* f2 = (g == 1 || g == 2) ? hi : lo;   // level-2: 0,1,1,0
#pragma unroll
        for (int d = 0; d < 10; ++d) F[g][d] = 0.f;
#pragma unroll
        for (int j2 = 0; j2 < 4; ++j2)
#pragma unroll
            for (int j1 = 0; j1 < 4; ++j1)
                F[g][2 * j2 + j1] = fmaf(f2[j2], f1[j1], F[g][2 * j2 + j1]);
    }
#pragma unroll
    for (int g = 0; g < 4; ++g)
#pragma unroll
        for (int d = 0; d < 10; ++d) F[g][d] = rfl(F[g][d]);

    // ---- load 7 (r,kc=tx) windows to regs: r = 2k+typ, 21 dwordx4 ----
    auto gload = [&](float4 st[7][3], int tileId) {
        const int ch  = tileId >> 9;
        const int rem = tileId & 511;
        const int tcc = rem >> 5;
        const int trr = rem & 31;
        const float* xc = x + (size_t)ch * HH * WW;
        const int cb = 128 * tcc + 4 * tx;           // window cols [cb-8, cb+3]
        int c0 = cb - 8;  if (c0 < 0) c0 += WW;      // wrap: tcc==0, tx<=1 only
        int c1 = cb - 4;  if (c1 < 0) c1 += WW;
#pragma unroll
        for (int k = 0; k < 7; ++k) {
            int grow = 64 * trr + 8 * w - 6 + 2 * k + typ;
            if (grow < 0) grow += HH;                // max = 2047, in bounds
            const float* rp = xc + (size_t)grow * WW;
            st[k][0] = *reinterpret_cast<const float4*>(rp + c0);
            st[k][1] = *reinterpret_cast<const float4*>(rp + c1);
            st[k][2] = *reinterpret_cast<const float4*>(rp + cb);
        }
    };

    // ---- row filter 7 rows into wave-private s[r][tx][g] ----
    auto rowfilt = [&](const float4 st[7][3]) {
#pragma unroll
        for (int k = 0; k < 7; ++k) {
            const float wv[12] = {st[k][0].x, st[k][0].y, st[k][0].z, st[k][0].w,
                                  st[k][1].x, st[k][1].y, st[k][1].z, st[k][1].w,
                                  st[k][2].x, st[k][2].y, st[k][2].z, st[k][2].w};
            float s0 = 0.f, s1 = 0.f, s2 = 0.f, s3 = 0.f;
#pragma unroll
            for (int dc = 0; dc < 10; ++dc) {
                const float v = wv[11 - dc];
                s0 = fmaf(F[0][dc], v, s0);
                s1 = fmaf(F[1][dc], v, s1);
                s2 = fmaf(F[2][dc], v, s2);
                s3 = fmaf(F[3][dc], v, s3);
            }
            float4 sv; sv.x = s0; sv.y = s1; sv.z = s2; sv.w = s3;
            const int r = 2 * k + typ;
            *reinterpret_cast<float4*>(&ws[(r * TKC + tx) * 4]) = sv;
        }
    };

    // ---- column pass: 10 ds_read_b128 + 160 FMA + 16 stores ----
    auto colpass = [&](int tileId) {
        const int ch  = tileId >> 9;
        const int rem = tileId & 511;
        const int tcc = rem >> 5;
        const int trr = rem & 31;

        float acc[4][4];
#pragma unroll
        for (int gi = 0; gi < 4; ++gi)
#pragma unroll
            for (int gj = 0; gj < 4; ++gj) acc[gi][gj] = 0.f;

#pragma unroll
        for (int u = 0; u < 10; ++u) {
            const float4 sv = *reinterpret_cast<const float4*>(
                &ws[((4 * typ + u) * TKC + tx) * 4]);
            const int dr = 9 - u;
#pragma unroll
            for (int gi = 0; gi < 4; ++gi) {
                const float fr = F[gi][dr];
                acc[gi][0] = fmaf(fr, sv.x, acc[gi][0]);
                acc[gi][1] = fmaf(fr, sv.y, acc[gi][1]);
                acc[gi][2] = fmaf(fr, sv.z, acc[gi][2]);
                acc[gi][3] = fmaf(fr, sv.w, acc[gi][3]);
            }
        }

        const int kr = TKR * trr + 2 * w + typ;
        const int kc = TKC * tcc + tx;
        const size_t plane = (size_t)OH * OW;
        float* op = out + (size_t)(ch * 16) * plane + (size_t)kr * OW + kc;
#pragma unroll
        for (int gi = 0; gi < 4; ++gi)
#pragma unroll
            for (int gj = 0; gj < 4; ++gj)
                __builtin_nontemporal_store(acc[gi][gj],
                                            op + (size_t)(gi * 4 + gj) * plane);
    };

    // ---- per-wave pipeline, no barriers anywhere ----
    // VMEM order per wave: L0(21) | L1(21) S0(16) | L2(21) S1(16) | S2(16)
    // WAITV(16) after colpass(i) drains the 21 loads (16 newer stores excluded).
    float4 st[7][3];

    gload(st, tile0 + 0);
    WAITV(0); SCHED0();
    rowfilt(st);
    WAITLGKM(); SCHED0();

    gload(st, tile0 + 1); SCHED0();
    colpass(tile0 + 0);
    WAITV(16); SCHED0();
    rowfilt(st);
    WAITLGKM(); SCHED0();

    gload(st, tile0 + 2); SCHED0();
    colpass(tile0 + 1);
    WAITV(16); SCHED0();
    rowfilt(st);
    WAITLGKM(); SCHED0();

    colpass(tile0 + 2);
}

extern "C" void kernel_launch(void* const* d_in, const int* in_sizes, int n_in,
                              void* d_out, int out_size, void* d_ws, size_t ws_size,
                              hipStream_t stream) {
    const float* x      = (const float*)d_in[0];
    const float* dec_lo = (const float*)d_in[1];
    const float* dec_hi = (const float*)d_in[2];
    float* out          = (float*)d_out;

    hipLaunchKernelGGL(wpt2_kernel, dim3(NBLK), dim3(512), 0, stream,
                       x, dec_lo, dec_hi, out);
}

// Round 18
// 21.445 us; speedup vs baseline: 1.0840x; 1.0840x over previous
//
#include <hip/hip_runtime.h>

#define HH 2048
#define WW 2048
#define OH 512
#define OW 512
#define TKC 32             // output cols per tile (threads x)
#define TKR 16             // output rows per tile (threads y)
#define SROWS 70           // row-filtered rows per tile (4*TKR + 6)
#define SSZ (SROWS * TKC * 4)   // s-buffer: [70][32][4g] = 8960 floats = 35 KB
#define NPAIR (SROWS * TKC)     // 2240 (r,kc) pairs per tile
#define NBLK 512           // 2 blocks/CU (2 x 35 KB LDS), all resident
#define TPB 3              // 512*3 = 1536 = 3ch * 16tcc * 32trr

#define BAR()     __builtin_amdgcn_s_barrier()
#define SCHED0()  __builtin_amdgcn_sched_barrier(0)
#define WAITV(n)  asm volatile("s_waitcnt vmcnt(" #n ")" ::: "memory")
#define WAITLGKM() asm volatile("s_waitcnt lgkmcnt(0)" ::: "memory")

__device__ __forceinline__ float rfl(float v) {
    return __int_as_float(__builtin_amdgcn_readfirstlane(__float_as_int(v)));
}

__global__ __launch_bounds__(512, 4)
void wpt2_kernel(const float* __restrict__ x,
                 const float* __restrict__ dec_lo,
                 const float* __restrict__ dec_hi,
                 float* __restrict__ out) {
    __shared__ float sA[SSZ];
    __shared__ float sB[SSZ];

    const int tx  = threadIdx.x;          // 0..31
    const int ty  = threadIdx.y;          // 0..15
    const int tid = ty * TKC + tx;

    // bijective XCD swizzle (512 % 8 == 0)
    const int bid = blockIdx.x;
    const int swz = (bid & 7) * (NBLK / 8) + (bid >> 3);
    const int tile0 = swz * TPB;   // tileId = (ch*16 + tcc)*32 + trr

    // ---- composed 10-tap filters (graycode band order), pinned to SGPRs ----
    float lo[4], hi[4];
#pragma unroll
    for (int j = 0; j < 4; ++j) { lo[j] = dec_lo[j]; hi[j] = dec_hi[j]; }
    float F[4][10];
#pragma unroll
    for (int g = 0; g < 4; ++g) {
        const float* f1 = (g >= 2) ? hi : lo;             // level-1: 0,0,1,1
        const float* f2 = (g == 1 || g == 2) ? hi : lo;   // level-2: 0,1,1,0
#pragma unroll
        for (int d = 0; d < 10; ++d) F[g][d] = 0.f;
#pragma unroll
        for (int j2 = 0; j2 < 4; ++j2)
#pragma unroll
            for (int j1 = 0; j1 < 4; ++j1)
                F[g][2 * j2 + j1] = fmaf(f2[j2], f1[j1], F[g][2 * j2 + j1]);
    }
#pragma unroll
    for (int g = 0; g < 4; ++g)
#pragma unroll
        for (int d = 0; d < 10; ++d) F[g][d] = rfl(F[g][d]);

    // ---- issue raw-x loads to REGISTERS for this thread's 5 (r,kc) pairs ----
    // pair p = k*512 + tid ; r = p>>5 (input row 0..69), kc = p&31 (out col)
    // window cols [4kc-8, 4kc+3] as three 16B chunks; all chunks in-bounds
    // (right edge: 128*15 + 4*31 + 3 = 2047).
    auto gload = [&](float4 st[5][3], int tileId) {
        const int ch  = tileId >> 9;
        const int rem = tileId & 511;
        const int tcc = rem >> 5;
        const int trr = rem & 31;
        const float* xc = x + (size_t)ch * HH * WW;
#pragma unroll
        for (int k = 0; k < 5; ++k) {
            const int p = k * 512 + tid;
            if (k < 4 || p < NPAIR) {
                const int r  = p >> 5;
                const int kc = p & 31;
                int grow = 64 * trr - 6 + r;  if (grow < 0) grow += HH;
                const float* rp = xc + (size_t)grow * WW;
                const int cb = 128 * tcc + 4 * kc;
                int c0 = cb - 8;  if (c0 < 0) c0 += WW;   // wrap: tcc==0,kc<=1 only
                int c1 = cb - 4;  if (c1 < 0) c1 += WW;
                st[k][0] = *reinterpret_cast<const float4*>(rp + c0);
                st[k][1] = *reinterpret_cast<const float4*>(rp + c1);
                st[k][2] = *reinterpret_cast<const float4*>(rp + cb);
            }
        }
    };

    // ---- row (horizontal) filter once per input row; write s[r][kc][g] ----
    // s[p][g] = sum_dc F[g][dc] * x[r][4kc+3-dc] ; w[i] = col 4kc-8+i
    auto rowfilt = [&](const float4 st[5][3], float* sbuf) {
#pragma unroll
        for (int k = 0; k < 5; ++k) {
            const int p = k * 512 + tid;
            if (k < 4 || p < NPAIR) {
                const float w[12] = {st[k][0].x, st[k][0].y, st[k][0].z, st[k][0].w,
                                     st[k][1].x, st[k][1].y, st[k][1].z, st[k][1].w,
                                     st[k][2].x, st[k][2].y, st[k][2].z, st[k][2].w};
                float s0 = 0.f, s1 = 0.f, s2 = 0.f, s3 = 0.f;
#pragma unroll
                for (int dc = 0; dc < 10; ++dc) {
                    const float v = w[11 - dc];
                    s0 = fmaf(F[0][dc], v, s0);
                    s1 = fmaf(F[1][dc], v, s1);
                    s2 = fmaf(F[2][dc], v, s2);
                    s3 = fmaf(F[3][dc], v, s3);
                }
                float4 sv; sv.x = s0; sv.y = s1; sv.z = s2; sv.w = s3;
                *reinterpret_cast<float4*>(&sbuf[p * 4]) = sv;   // ds_write_b128
            }
        }
    };

    // ---- column (vertical) pass: 10 ds_read_b128 + 160 FMA + 16 stores ----
    // out row kr needs s rows 4ty..4ty+9 (local): dr = 9-u.
    auto colpass = [&](const float* sbuf, int tileId) {
        const int ch  = tileId >> 9;
        const int rem = tileId & 511;
        const int tcc = rem >> 5;
        const int trr = rem & 31;

        __builtin_amdgcn_s_setprio(1);
        float acc[4][4];
#pragma unroll
        for (int gi = 0; gi < 4; ++gi)
#pragma unroll
            for (int gj = 0; gj < 4; ++gj) acc[gi][gj] = 0.f;

#pragma unroll
        for (int u = 0; u < 10; ++u) {
            const float4 sv = *reinterpret_cast<const float4*>(
                &sbuf[((4 * ty + u) * TKC + tx) * 4]);
            const int dr = 9 - u;
#pragma unroll
            for (int gi = 0; gi < 4; ++gi) {
                const float fr = F[gi][dr];
                acc[gi][0] = fmaf(fr, sv.x, acc[gi][0]);
                acc[gi][1] = fmaf(fr, sv.y, acc[gi][1]);
                acc[gi][2] = fmaf(fr, sv.z, acc[gi][2]);
                acc[gi][3] = fmaf(fr, sv.w, acc[gi][3]);
            }
        }

        const int kr = TKR * trr + ty;
        const int kc = TKC * tcc + tx;
        const size_t plane = (size_t)OH * OW;
        float* op = out + (size_t)(ch * 16) * plane + (size_t)kr * OW + kc;
#pragma unroll
        for (int gi = 0; gi < 4; ++gi)
#pragma unroll
            for (int gj = 0; gj < 4; ++gj)
                __builtin_nontemporal_store(acc[gi][gj],
                                            op + (size_t)(gi * 4 + gj) * plane);
        __builtin_amdgcn_s_setprio(0);
    };

    // ---- pipeline: loads(i+1) issued before colpass(i); rowfilt after drain ----
    float4 st[5][3];

    gload(st, tile0 + 0);
    WAITV(0);
    rowfilt(st, sA);
    WAITLGKM(); BAR(); SCHED0();

    gload(st, tile0 + 1); SCHED0();      // pin loads before colpass
    colpass(sA, tile0 + 0);
    WAITV(16);                           // drain 15 loads; 16 newer stores excluded
    rowfilt(st, sB);
    WAITLGKM(); BAR(); SCHED0();

    gload(st, tile0 + 2); SCHED0();
    colpass(sB, tile0 + 1);
    WAITV(16);
    rowfilt(st, sA);
    WAITLGKM(); BAR(); SCHED0();

    colpass(sA, tile0 + 2);
}

extern "C" void kernel_launch(void* const* d_in, const int* in_sizes, int n_in,
                              void* d_out, int out_size, void* d_ws, size_t ws_size,
                              hipStream_t stream) {
    const float* x      = (const float*)d_in[0];
    const float* dec_lo = (const float*)d_in[1];
    const float* dec_hi = (const float*)d_in[2];
    float* out          = (float*)d_out;

    hipLaunchKernelGGL(wpt2_kernel, dim3(NBLK), dim3(TKC, TKR), 0, stream,
                       x, dec_lo, dec_hi, out);
}

// Round 19
// 21.429 us; speedup vs baseline: 1.0848x; 1.0007x over previous
//
#include <hip/hip_runtime.h>

#define HH 2048
#define WW 2048
#define OH 512
#define OW 512
#define TKC 32             // output cols per tile (threads x)
#define TKR 16             // output rows per tile (threads y)
#define SROWS 70           // row-filtered rows per tile (4*TKR + 6)
#define SSZ (SROWS * TKC * 4)   // s-buffer: [70][32][4g] = 8960 floats = 35 KB
#define NPAIR (SROWS * TKC)     // 2240 (r,kc) pairs per tile
#define NBLK 512           // 2 blocks/CU (2 x 35 KB LDS), all resident
#define TPB 3              // 512*3 = 1536 = 3ch * 16tcc * 32trr

#define BAR()     __builtin_amdgcn_s_barrier()
#define SCHED0()  __builtin_amdgcn_sched_barrier(0)
#define WAITV(n)  asm volatile("s_waitcnt vmcnt(" #n ")" ::: "memory")
#define WAITLGKM() asm volatile("s_waitcnt lgkmcnt(0)" ::: "memory")

__device__ __forceinline__ float rfl(float v) {
    return __int_as_float(__builtin_amdgcn_readfirstlane(__float_as_int(v)));
}

__global__ __launch_bounds__(512, 4)
void wpt2_kernel(const float* __restrict__ x,
                 const float* __restrict__ dec_lo,
                 const float* __restrict__ dec_hi,
                 float* __restrict__ out) {
    __shared__ float sA[SSZ];
    __shared__ float sB[SSZ];

    const int tx  = threadIdx.x;          // 0..31
    const int ty  = threadIdx.y;          // 0..15
    const int tid = ty * TKC + tx;

    // bijective XCD swizzle (512 % 8 == 0)
    const int bid = blockIdx.x;
    const int swz = (bid & 7) * (NBLK / 8) + (bid >> 3);
    const int tile0 = swz * TPB;   // tileId = (ch*16 + tcc)*32 + trr

    // ---- composed 10-tap filters (graycode band order), pinned to SGPRs ----
    float lo[4], hi[4];
#pragma unroll
    for (int j = 0; j < 4; ++j) { lo[j] = dec_lo[j]; hi[j] = dec_hi[j]; }
    float F[4][10];
#pragma unroll
    for (int g = 0; g < 4; ++g) {
        const float* f1 = (g >= 2) ? hi : lo;             // level-1: 0,0,1,1
        const float* f2 = (g == 1 || g == 2) ? hi : lo;   // level-2: 0,1,1,0
#pragma unroll
        for (int d = 0; d < 10; ++d) F[g][d] = 0.f;
#pragma unroll
        for (int j2 = 0; j2 < 4; ++j2)
#pragma unroll
            for (int j1 = 0; j1 < 4; ++j1)
                F[g][2 * j2 + j1] = fmaf(f2[j2], f1[j1], F[g][2 * j2 + j1]);
    }
#pragma unroll
    for (int g = 0; g < 4; ++g)
#pragma unroll
        for (int d = 0; d < 10; ++d) F[g][d] = rfl(F[g][d]);

    // ---- issue raw-x loads to REGISTERS for this thread's 5 (r,kc) pairs ----
    auto gload = [&](float4 st[5][3], int tileId) {
        const int ch  = tileId >> 9;
        const int rem = tileId & 511;
        const int tcc = rem >> 5;
        const int trr = rem & 31;
        const float* xc = x + (size_t)ch * HH * WW;
#pragma unroll
        for (int k = 0; k < 5; ++k) {
            const int p = k * 512 + tid;
            if (k < 4 || p < NPAIR) {
                const int r  = p >> 5;
                const int kc = p & 31;
                int grow = 64 * trr - 6 + r;  if (grow < 0) grow += HH;
                const float* rp = xc + (size_t)grow * WW;
                const int cb = 128 * tcc + 4 * kc;
                int c0 = cb - 8;  if (c0 < 0) c0 += WW;   // wrap: tcc==0,kc<=1 only
                int c1 = cb - 4;  if (c1 < 0) c1 += WW;
                st[k][0] = *reinterpret_cast<const float4*>(rp + c0);
                st[k][1] = *reinterpret_cast<const float4*>(rp + c1);
                st[k][2] = *reinterpret_cast<const float4*>(rp + cb);
            }
        }
    };

    // ---- row (horizontal) filter once per input row; write s[r][kc][g] ----
    auto rowfilt = [&](const float4 st[5][3], float* sbuf) {
#pragma unroll
        for (int k = 0; k < 5; ++k) {
            const int p = k * 512 + tid;
            if (k < 4 || p < NPAIR) {
                const float w[12] = {st[k][0].x, st[k][0].y, st[k][0].z, st[k][0].w,
                                     st[k][1].x, st[k][1].y, st[k][1].z, st[k][1].w,
                                     st[k][2].x, st[k][2].y, st[k][2].z, st[k][2].w};
                float s0 = 0.f, s1 = 0.f, s2 = 0.f, s3 = 0.f;
#pragma unroll
                for (int dc = 0; dc < 10; ++dc) {
                    const float v = w[11 - dc];
                    s0 = fmaf(F[0][dc], v, s0);
                    s1 = fmaf(F[1][dc], v, s1);
                    s2 = fmaf(F[2][dc], v, s2);
                    s3 = fmaf(F[3][dc], v, s3);
                }
                float4 sv; sv.x = s0; sv.y = s1; sv.z = s2; sv.w = s3;
                *reinterpret_cast<float4*>(&sbuf[p * 4]) = sv;   // ds_write_b128
            }
        }
    };

    // ---- column (vertical) pass: 10 ds_read_b128 + 160 FMA + 16 stores ----
    auto colpass = [&](const float* sbuf, int tileId) {
        const int ch  = tileId >> 9;
        const int rem = tileId & 511;
        const int tcc = rem >> 5;
        const int trr = rem & 31;

        __builtin_amdgcn_s_setprio(1);
        float acc[4][4];
#pragma unroll
        for (int gi = 0; gi < 4; ++gi)
#pragma unroll
            for (int gj = 0; gj < 4; ++gj) acc[gi][gj] = 0.f;

#pragma unroll
        for (int u = 0; u < 10; ++u) {
            const float4 sv = *reinterpret_cast<const float4*>(
                &sbuf[((4 * ty + u) * TKC + tx) * 4]);
            const int dr = 9 - u;
#pragma unroll
            for (int gi = 0; gi < 4; ++gi) {
                const float fr = F[gi][dr];
                acc[gi][0] = fmaf(fr, sv.x, acc[gi][0]);
                acc[gi][1] = fmaf(fr, sv.y, acc[gi][1]);
                acc[gi][2] = fmaf(fr, sv.z, acc[gi][2]);
                acc[gi][3] = fmaf(fr, sv.w, acc[gi][3]);
            }
        }

        const int kr = TKR * trr + ty;
        const int kc = TKC * tcc + tx;
        const size_t plane = (size_t)OH * OW;
        float* op = out + (size_t)(ch * 16) * plane + (size_t)kr * OW + kc;
#pragma unroll
        for (int gi = 0; gi < 4; ++gi)
#pragma unroll
            for (int gj = 0; gj < 4; ++gj)
                __builtin_nontemporal_store(acc[gi][gj],
                                            op + (size_t)(gi * 4 + gj) * plane);
        __builtin_amdgcn_s_setprio(0);
    };

    // ---- pipeline; second co-resident block (bid&256) de-phased ~3.2 µs ----
    float4 st[5][3];

    gload(st, tile0 + 0);
    if (bid & 256) __builtin_amdgcn_s_sleep(120);   // loads land during sleep
    WAITV(0);
    rowfilt(st, sA);
    WAITLGKM(); BAR(); SCHED0();

    gload(st, tile0 + 1); SCHED0();      // pin loads before colpass
    colpass(sA, tile0 + 0);
    WAITV(16);                           // drain 15 loads; 16 newer stores excluded
    rowfilt(st, sB);
    WAITLGKM(); BAR(); SCHED0();

    gload(st, tile0 + 2); SCHED0();
    colpass(sB, tile0 + 1);
    WAITV(16);
    rowfilt(st, sA);
    WAITLGKM(); BAR(); SCHED0();

    colpass(sA, tile0 + 2);
}

extern "C" void kernel_launch(void* const* d_in, const int* in_sizes, int n_in,
                              void* d_out, int out_size, void* d_ws, size_t ws_size,
                              hipStream_t stream) {
    const float* x      = (const float*)d_in[0];
    const float* dec_lo = (const float*)d_in[1];
    const float* dec_hi = (const float*)d_in[2];
    float* out          = (float*)d_out;

    hipLaunchKernelGGL(wpt2_kernel, dim3(NBLK), dim3(TKC, TKR), 0, stream,
                       x, dec_lo, dec_hi, out);
}